// Round 1
// baseline (7336.891 us; speedup 1.0000x reference)
//
#include <hip/hip_runtime.h>

// RNN: h_t = tanh(xs_t @ Wih + bih + h_{t-1} @ Whh + bhh), out = stacked h_t.
// T=512, B=64, D=H=1024. Inputs fp32; compute via split-fp16 MFMA (hi+lo planes,
// 3 MFMAs per fragment pair) for ~1e-5 absolute accuracy.
//
// ws layout (total ~8.9 MiB):
//   WIH planes: Wih transposed to [j][k], tiled 128x32 per (bn,bk), XOR-swizzled
//   WHH planes: Whh as [col][k] rows of 2 KiB, byte addr col*2048 + ((2k)^((col&7)<<4))
//   bias = bih+bhh, h ping-pong planes (hi0,lo0,hi1,lo1), barrier state.

typedef unsigned int u32;
typedef _Float16 f16;
typedef _Float16 f16x8 __attribute__((ext_vector_type(8)));
typedef float f32x4 __attribute__((ext_vector_type(4)));

typedef const __attribute__((address_space(1))) u32* gptr_t;
typedef __attribute__((address_space(3))) u32* lptr_t;

#define WS_WIH_HI 0UL
#define WS_WIH_LO 2097152UL
#define WS_WHH_HI 4194304UL
#define WS_WHH_LO 6291456UL
#define WS_BIAS   8388608UL
#define WS_HBUF   8392704UL   // 4 planes x 131072 B: hi0, lo0, hi1, lo1
#define WS_BAR    8916992UL   // 2 ints

__device__ __forceinline__ void gld16(const void* g, void* l){
  __builtin_amdgcn_global_load_lds((gptr_t)g, (lptr_t)l, 16, 0, 0);
}

__device__ __forceinline__ float fast_tanh(float x){
  float ax = __builtin_fabsf(x);
  float e  = __expf(-2.0f * ax);
  float r  = (1.0f - e) / (1.0f + e);
  return x < 0.0f ? -r : r;
}

// ---- Wih -> transposed ([j][k]) tiled 128x32 hi/lo planes, XOR-swizzled ----
__global__ __launch_bounds__(256) void k_split_wih(const float* __restrict__ W, char* __restrict__ ws){
  f16* hi = (f16*)(ws + WS_WIH_HI);
  f16* lo = (f16*)(ws + WS_WIH_LO);
  int o = (blockIdx.x * 256 + threadIdx.x) * 8;   // half index < 1048576
  int tile = o >> 12;          // 4096 halves per tile (8 KiB)
  int ih   = o & 4095;
  int col  = ih >> 5;          // 0..127 within tile
  int slotp = (ih & 31) >> 3;  // stored slot
  int slot  = slotp ^ (col & 3);
  int bn = tile >> 5, bk = tile & 31;
  int k0 = bk * 32 + slot * 8;
  int j  = bn * 128 + col;
  f16x8 h8, l8;
  #pragma unroll
  for (int e = 0; e < 8; e++){
    float v = W[(k0 + e) * 1024 + j];   // Wih is [D][H] row-major
    f16 h = (f16)v;
    h8[e] = h;
    l8[e] = (f16)(v - (float)h);
  }
  *(f16x8*)(hi + o) = h8;
  *(f16x8*)(lo + o) = l8;
}

// ---- Whh -> [col][k] hi/lo planes, byte addr col*2048 + ((2k)^((col&7)<<4)) ----
__global__ __launch_bounds__(256) void k_split_whh(const float* __restrict__ W, char* __restrict__ ws){
  f16* hi = (f16*)(ws + WS_WHH_HI);
  f16* lo = (f16*)(ws + WS_WHH_LO);
  int o = (blockIdx.x * 256 + threadIdx.x) * 8;   // half index < 1048576
  int col = o >> 10;
  int q2  = (o & 1023) * 2;                // byte offset in the col row, 16-aligned
  int kb2 = q2 ^ ((col & 7) << 4);
  int k0  = kb2 >> 1;
  f16x8 h8, l8;
  #pragma unroll
  for (int e = 0; e < 8; e++){
    float v = W[(k0 + e) * 1024 + col];   // Whh is [H][H] row-major, h@Whh -> col j
    f16 h = (f16)v;
    h8[e] = h;
    l8[e] = (f16)(v - (float)h);
  }
  *(f16x8*)(hi + o) = h8;
  *(f16x8*)(lo + o) = l8;
}

// ---- bias = bih + bhh; h0 hi/lo planes from init; barrier init ----
__global__ __launch_bounds__(256) void k_prep(const float* __restrict__ bih, const float* __restrict__ bhh,
                                              const float* __restrict__ init, char* __restrict__ ws){
  int i = blockIdx.x * 256 + threadIdx.x;   // grid = 256 blocks -> 65536 threads
  float* bias = (float*)(ws + WS_BIAS);
  f16* h0h = (f16*)(ws + WS_HBUF);
  f16* h0l = (f16*)(ws + WS_HBUF + 131072UL);
  if (i < 1024) bias[i] = bih[i] + bhh[i];
  float v = init[i];
  f16 h = (f16)v;
  h0h[i] = h;
  h0l[i] = (f16)(v - (float)h);
  if (i == 0){ int* bar = (int*)(ws + WS_BAR); bar[0] = 0; bar[1] = 0; }
}

// ---- pre = xs @ Wih + bias -> out (in place of final output) ----
// 128x128 tile, BK=32, 4 waves, split-fp16: A reg-staged from fp32 xs (split+swizzled
// ds_write), B via global_load_lds from pre-split planes. 2048 blocks.
__global__ __launch_bounds__(256) void k_gemm(const float* __restrict__ xs, const char* __restrict__ ws,
                                              float* __restrict__ out){
  __shared__ char lds[65536];   // 2 bufs x [Ahi 8K | Alo 8K | Bhi 8K | Blo 8K]
  const int tid = threadIdx.x;
  const int w = tid >> 6, lane = tid & 63;
  const int bid = blockIdx.x;
  const int id = ((bid & 7) << 8) | (bid >> 3);   // XCD-chunked swizzle (2048 = 8*256)
  const int bm = id >> 3, bn = id & 7;
  const int qr = w >> 1, qc = w & 1;

  const int sw = ((lane >> 4) ^ (lane & 3)) << 4;
  int aoff[4], boff[4];
  #pragma unroll
  for (int r = 0; r < 4; r++) aoff[r] = (qr*64 + r*16 + (lane & 15)) * 64 + sw;
  #pragma unroll
  for (int c = 0; c < 4; c++) boff[c] = (qc*64 + c*16 + (lane & 15)) * 64 + sw;

  f32x4 acc[4][4];
  #pragma unroll
  for (int r = 0; r < 4; r++)
    #pragma unroll
    for (int c = 0; c < 4; c++) acc[r][c] = (f32x4){0.f, 0.f, 0.f, 0.f};

  const int rowA = tid >> 1, halfA = tid & 1;
  const float* asrc = xs + (long)(bm*128 + rowA) * 1024 + halfA * 16;
  f32x4 a4[4];

  auto loadA = [&](int kt){
    const float* s = asrc + kt * 32;
    #pragma unroll
    for (int i = 0; i < 4; i++) a4[i] = *(const f32x4*)(s + i*4);
  };
  auto writeA = [&](int buf){
    char* base = lds + buf * 32768;
    f16x8 hh0, hh1, ll0, ll1;
    #pragma unroll
    for (int i = 0; i < 16; i++){
      float v = a4[i >> 2][i & 3];
      f16 h = (f16)v;
      f16 l = (f16)(v - (float)h);
      if (i < 8){ hh0[i] = h; ll0[i] = l; } else { hh1[i & 7] = h; ll1[i & 7] = l; }
    }
    int s0 = ((2*halfA)     ^ (rowA & 3)) << 4;
    int s1 = ((2*halfA + 1) ^ (rowA & 3)) << 4;
    *(f16x8*)(base + rowA*64 + s0)        = hh0;
    *(f16x8*)(base + rowA*64 + s1)        = hh1;
    *(f16x8*)(base + 8192 + rowA*64 + s0) = ll0;
    *(f16x8*)(base + 8192 + rowA*64 + s1) = ll1;
  };
  const char* bhig = ws + WS_WIH_HI;
  const char* blog = ws + WS_WIH_LO;
  auto stageB = [&](int buf, int kt){
    long toff = (long)(bn*32 + kt) * 8192;
    #pragma unroll
    for (int i = 0; i < 4; i++){
      int off = (w*4 + i) << 10;   // 0..16383 over the two B planes
      const char* g = (off < 8192) ? (bhig + toff + off) : (blog + toff + (off - 8192));
      gld16(g + lane*16, lds + buf*32768 + 16384 + off);
    }
  };
  auto compute = [&](int buf){
    const char* base = lds + buf * 32768;
    f16x8 ah[4], al[4], bh[4], bl[4];
    #pragma unroll
    for (int r = 0; r < 4; r++){
      ah[r] = *(const f16x8*)(base + aoff[r]);
      al[r] = *(const f16x8*)(base + 8192 + aoff[r]);
    }
    #pragma unroll
    for (int c = 0; c < 4; c++){
      bh[c] = *(const f16x8*)(base + 16384 + boff[c]);
      bl[c] = *(const f16x8*)(base + 24576 + boff[c]);
    }
    #pragma unroll
    for (int r = 0; r < 4; r++)
      #pragma unroll
      for (int c = 0; c < 4; c++){
        acc[r][c] = __builtin_amdgcn_mfma_f32_16x16x32_f16(ah[r], bh[c], acc[r][c], 0, 0, 0);
        acc[r][c] = __builtin_amdgcn_mfma_f32_16x16x32_f16(ah[r], bl[c], acc[r][c], 0, 0, 0);
        acc[r][c] = __builtin_amdgcn_mfma_f32_16x16x32_f16(al[r], bh[c], acc[r][c], 0, 0, 0);
      }
  };

  loadA(0);
  stageB(0, 0);
  writeA(0);
  __syncthreads();
  #pragma unroll 2
  for (int kt = 0; kt < 32; kt++){
    const int buf = kt & 1;
    if (kt < 31){
      loadA(kt + 1);
      stageB(buf ^ 1, kt + 1);
    }
    compute(buf);
    if (kt < 31) writeA(buf ^ 1);
    __syncthreads();
  }

  const float* bias = (const float*)(ws + WS_BIAS);
  #pragma unroll
  for (int r = 0; r < 4; r++){
    int row0 = qr*64 + r*16 + ((lane >> 4) << 2);
    long gibase = ((long)bm*128 + row0) * 1024;
    #pragma unroll
    for (int c = 0; c < 4; c++){
      int gj = (bn << 7) + qc*64 + c*16 + (lane & 15);
      float bj = bias[gj];
      #pragma unroll
      for (int rr = 0; rr < 4; rr++)
        out[gibase + (long)rr*1024 + gj] = acc[r][c][rr] + bj;
    }
  }
}

// ---- recurrence: 128 WGs x 128 thr (cooperative). WG = 16 cols x 32 rows.
// Whh slice resident in LDS; h exchanged via global fp16 hi/lo ping-pong planes.
__global__ __launch_bounds__(128) void k_rnn(char* __restrict__ ws, float* __restrict__ out){
  __shared__ char ldsB[65536];   // Bhi [16 cols x 1024 k] (32K) | Blo (32K), swizzled
  const int tid = threadIdx.x;
  const int w = tid >> 6, lane = tid & 63;
  const int wg = blockIdx.x;        // 0..127
  const int cg = wg & 63, rg = wg >> 6;
  const int j0 = cg << 4;           // 16 columns
  const int r0 = (rg << 5) + (w << 4);   // this wave's 16 rows

  {
    const char* gH = ws + WS_WHH_HI + (long)j0 * 2048;
    const char* gL = ws + WS_WHH_LO + (long)j0 * 2048;
    #pragma unroll
    for (int i = 0; i < 16; i++){
      int off = (w*16 + i) << 10;   // 0..32767
      gld16(gH + off + lane*16, ldsB + off);
      gld16(gL + off + lane*16, ldsB + 32768 + off);
    }
  }
  __syncthreads();

  f16* hp0 = (f16*)(ws + WS_HBUF);
  f16* hp1 = (f16*)(ws + WS_HBUF + 131072UL);
  f16* hp2 = (f16*)(ws + WS_HBUF + 262144UL);
  f16* hp3 = (f16*)(ws + WS_HBUF + 393216UL);
  int* bar = (int*)(ws + WS_BAR);

  const int colL  = lane & 15;
  const int kg    = (lane >> 4) << 3;
  const int myrow = r0 + colL;
  const int bmask = (colL & 7) << 4;
  const long bbase = (long)colL * 2048;
  const int rowe = r0 + ((lane >> 4) << 2);
  const int col  = j0 + colL;

  int parity = 0;

  for (int t = 0; t < 512; t++){
    const int cur = t & 1;
    const f16* Ah = cur ? hp2 : hp0;
    const f16* Al = cur ? hp3 : hp1;
    f16* Nh = cur ? hp0 : hp2;
    f16* Nl = cur ? hp1 : hp3;

    const f16* aH = Ah + (long)myrow * 1024 + kg;
    const f16* aL = Al + (long)myrow * 1024 + kg;

    f32x4 acc0 = (f32x4){0.f,0.f,0.f,0.f};
    f32x4 acc1 = (f32x4){0.f,0.f,0.f,0.f};
    #pragma unroll 8
    for (int ks = 0; ks < 32; ks++){
      f16x8 avh = *(const f16x8*)(aH + ks*32);
      f16x8 avl = *(const f16x8*)(aL + ks*32);
      int kb = ((ks*32 + kg) * 2) ^ bmask;
      f16x8 bvh = *(const f16x8*)(ldsB + bbase + kb);
      f16x8 bvl = *(const f16x8*)(ldsB + 32768 + bbase + kb);
      if (ks & 1){
        acc1 = __builtin_amdgcn_mfma_f32_16x16x32_f16(avh, bvh, acc1, 0, 0, 0);
        acc1 = __builtin_amdgcn_mfma_f32_16x16x32_f16(avh, bvl, acc1, 0, 0, 0);
        acc1 = __builtin_amdgcn_mfma_f32_16x16x32_f16(avl, bvh, acc1, 0, 0, 0);
      } else {
        acc0 = __builtin_amdgcn_mfma_f32_16x16x32_f16(avh, bvh, acc0, 0, 0, 0);
        acc0 = __builtin_amdgcn_mfma_f32_16x16x32_f16(avh, bvl, acc0, 0, 0, 0);
        acc0 = __builtin_amdgcn_mfma_f32_16x16x32_f16(avl, bvh, acc0, 0, 0, 0);
      }
    }
    f32x4 acc = acc0 + acc1;

    long obase = ((long)t << 16) + (long)rowe * 1024 + col;
    #pragma unroll
    for (int rr = 0; rr < 4; rr++){
      float pre = out[obase + rr*1024];
      float hv = fast_tanh(pre + acc[rr]);
      out[obase + rr*1024] = hv;
      f16 hh = (f16)hv;
      int hidx = (rowe + rr) * 1024 + col;
      Nh[hidx] = hh;
      Nl[hidx] = (f16)(hv - (float)hh);
    }

    if (t < 511){
      parity ^= 1;
      __syncthreads();   // all WG stores complete (waitcnt before barrier)
      if (tid == 0){
        // acq_rel agent RMW: release flushes this XCD's L2 (h stores), acquire invalidates
        if (__hip_atomic_fetch_add(&bar[0], 1, __ATOMIC_ACQ_REL, __HIP_MEMORY_SCOPE_AGENT) == 127){
          __hip_atomic_store(&bar[0], 0, __ATOMIC_RELAXED, __HIP_MEMORY_SCOPE_AGENT);
          __hip_atomic_store(&bar[1], parity, __ATOMIC_RELEASE, __HIP_MEMORY_SCOPE_AGENT);
        } else {
          while (__hip_atomic_load(&bar[1], __ATOMIC_RELAXED, __HIP_MEMORY_SCOPE_AGENT) != parity)
            __builtin_amdgcn_s_sleep(1);
          (void)__hip_atomic_load(&bar[1], __ATOMIC_ACQUIRE, __HIP_MEMORY_SCOPE_AGENT);
        }
      }
      __syncthreads();
    }
  }
}

extern "C" void kernel_launch(void* const* d_in, const int* in_sizes, int n_in,
                              void* d_out, int out_size, void* d_ws, size_t ws_size,
                              hipStream_t stream){
  const float* init = (const float*)d_in[0];
  const float* xs   = (const float*)d_in[1];
  const float* Wih  = (const float*)d_in[2];
  const float* bih  = (const float*)d_in[3];
  const float* Whh  = (const float*)d_in[4];
  const float* bhh  = (const float*)d_in[5];
  float* out = (float*)d_out;
  char* ws = (char*)d_ws;
  (void)in_sizes; (void)n_in; (void)out_size; (void)ws_size;   // needs ~8.9 MiB ws

  hipLaunchKernelGGL(k_split_wih, dim3(512),  dim3(256), 0, stream, Wih, ws);
  hipLaunchKernelGGL(k_split_whh, dim3(512),  dim3(256), 0, stream, Whh, ws);
  hipLaunchKernelGGL(k_prep,      dim3(256),  dim3(256), 0, stream, bih, bhh, init, ws);
  hipLaunchKernelGGL(k_gemm,      dim3(2048), dim3(256), 0, stream, xs, (const char*)ws, out);

  void* kargs[] = { (void*)&ws, (void*)&out };
  hipLaunchCooperativeKernel((const void*)k_rnn, dim3(128), dim3(128), kargs, 0, stream);
}

// Round 3
// 4916.196 us; speedup vs baseline: 1.4924x; 1.4924x over previous
//
#include <hip/hip_runtime.h>

// RNN: h_t = tanh(xs_t @ Wih + bih + h_{t-1} @ Whh + bhh), out = stacked h_t.
// T=512, B=64, D=H=1024. fp32 in/out; compute via split-fp16 MFMA (hi+lo, 3 terms).
//
// Recurrence: 4 INDEPENDENT row-groups (16 rows each) x 32 col-WGs (32 cols each).
// Per-group monotonic-counter barrier (ONE inc per WG — lane0-guarded; round-2 bug
// was all 64 lanes incrementing, making the barrier a no-op). h exchanged as packed
// u32 (hi,lo f16) via SYSTEM-scope relaxed atomics (sc0 sc1 -> coherent through the
// memory-side cache; no L2 flush/invalidate anywhere in the loop).

typedef unsigned int u32;
typedef unsigned long long u64;
typedef unsigned short u16;
typedef _Float16 f16;
typedef _Float16 f16x8 __attribute__((ext_vector_type(8)));
typedef float f32x4 __attribute__((ext_vector_type(4)));
typedef u32 u32x4 __attribute__((ext_vector_type(4)));

typedef const __attribute__((address_space(1))) u32* gptr_t;
typedef __attribute__((address_space(3))) u32* lptr_t;

#define WS_WIH_HI 0UL
#define WS_WIH_LO 2097152UL
#define WS_WHH_HI 4194304UL
#define WS_WHH_LO 6291456UL
#define WS_BIAS   8388608UL
#define WS_HBUF   8392704UL   // 2 packed h planes x 262144 B (u32 = lo16:hi16 -> hi f16, lo f16)
#define WS_BAR    8916992UL   // 4 group counters at 128 B stride

__device__ __forceinline__ void gld16(const void* g, void* l){
  __builtin_amdgcn_global_load_lds((gptr_t)g, (lptr_t)l, 16, 0, 0);
}

__device__ __forceinline__ float fast_tanh(float x){
  float ax = __builtin_fabsf(x);
  float e  = __expf(-2.0f * ax);
  float r  = (1.0f - e) / (1.0f + e);
  return x < 0.0f ? -r : r;
}

__device__ __forceinline__ u64 cload(const u64* p){
  return __hip_atomic_load(p, __ATOMIC_RELAXED, __HIP_MEMORY_SCOPE_SYSTEM);
}
__device__ __forceinline__ void cstore(u32* p, u32 v){
  __hip_atomic_store(p, v, __ATOMIC_RELAXED, __HIP_MEMORY_SCOPE_SYSTEM);
}
__device__ __forceinline__ u32 packf16(float v){
  f16 h = (f16)v;
  f16 l = (f16)(v - (float)h);
  return (u32)__builtin_bit_cast(u16, h) | ((u32)__builtin_bit_cast(u16, l) << 16);
}

// ---- Wih -> transposed ([j][k]) tiled 128x32 hi/lo planes, XOR-swizzled (for k_gemm) ----
__global__ __launch_bounds__(256) void k_split_wih(const float* __restrict__ W, char* __restrict__ ws){
  f16* hi = (f16*)(ws + WS_WIH_HI);
  f16* lo = (f16*)(ws + WS_WIH_LO);
  int o = (blockIdx.x * 256 + threadIdx.x) * 8;
  int tile = o >> 12;
  int ih   = o & 4095;
  int col  = ih >> 5;
  int slotp = (ih & 31) >> 3;
  int slot  = slotp ^ (col & 3);
  int bn = tile >> 5, bk = tile & 31;
  int k0 = bk * 32 + slot * 8;
  int j  = bn * 128 + col;
  f16x8 h8, l8;
  #pragma unroll
  for (int e = 0; e < 8; e++){
    float v = W[(k0 + e) * 1024 + j];
    f16 h = (f16)v;
    h8[e] = h;
    l8[e] = (f16)(v - (float)h);
  }
  *(f16x8*)(hi + o) = h8;
  *(f16x8*)(lo + o) = l8;
}

// ---- Whh -> [col][k] planes: hi XOR-swizzled (LDS staging), lo LINEAR (L2 direct reads) ----
__global__ __launch_bounds__(256) void k_split_whh(const float* __restrict__ W, char* __restrict__ ws){
  f16* hi = (f16*)(ws + WS_WHH_HI);
  f16* lo = (f16*)(ws + WS_WHH_LO);
  int o = (blockIdx.x * 256 + threadIdx.x) * 8;
  int col = o >> 10;
  int q2  = (o & 1023) * 2;
  int k0h = (q2 ^ ((col & 7) << 4)) >> 1;
  int k0l = q2 >> 1;
  f16x8 h8, l8;
  #pragma unroll
  for (int e = 0; e < 8; e++){
    float vh = W[(k0h + e) * 1024 + col];
    h8[e] = (f16)vh;
    float vl = W[(k0l + e) * 1024 + col];
    l8[e] = (f16)(vl - (float)(f16)vl);
  }
  *(f16x8*)(hi + o) = h8;
  *(f16x8*)(lo + o) = l8;
}

// ---- bias = bih+bhh; packed h(0) plane; zero the 4 group counters ----
__global__ __launch_bounds__(256) void k_prep(const float* __restrict__ bih, const float* __restrict__ bhh,
                                              const float* __restrict__ init, char* __restrict__ ws){
  int i = blockIdx.x * 256 + threadIdx.x;   // 65536 threads
  float* bias = (float*)(ws + WS_BIAS);
  u32* pk0 = (u32*)(ws + WS_HBUF);
  if (i < 1024) bias[i] = bih[i] + bhh[i];
  pk0[i] = packf16(init[i]);
  if (i < 4) ((u32*)(ws + WS_BAR))[i * 32] = 0;
}

// ---- pre = xs @ Wih + bias -> out (verified round 1, unchanged) ----
__global__ __launch_bounds__(256) void k_gemm(const float* __restrict__ xs, const char* __restrict__ ws,
                                              float* __restrict__ out){
  __shared__ char lds[65536];
  const int tid = threadIdx.x;
  const int w = tid >> 6, lane = tid & 63;
  const int bid = blockIdx.x;
  const int id = ((bid & 7) << 8) | (bid >> 3);
  const int bm = id >> 3, bn = id & 7;
  const int qr = w >> 1, qc = w & 1;

  const int sw = ((lane >> 4) ^ (lane & 3)) << 4;
  int aoff[4], boff[4];
  #pragma unroll
  for (int r = 0; r < 4; r++) aoff[r] = (qr*64 + r*16 + (lane & 15)) * 64 + sw;
  #pragma unroll
  for (int c = 0; c < 4; c++) boff[c] = (qc*64 + c*16 + (lane & 15)) * 64 + sw;

  f32x4 acc[4][4];
  #pragma unroll
  for (int r = 0; r < 4; r++)
    #pragma unroll
    for (int c = 0; c < 4; c++) acc[r][c] = (f32x4){0.f, 0.f, 0.f, 0.f};

  const int rowA = tid >> 1, halfA = tid & 1;
  const float* asrc = xs + (long)(bm*128 + rowA) * 1024 + halfA * 16;
  f32x4 a4[4];

  auto loadA = [&](int kt){
    const float* s = asrc + kt * 32;
    #pragma unroll
    for (int i = 0; i < 4; i++) a4[i] = *(const f32x4*)(s + i*4);
  };
  auto writeA = [&](int buf){
    char* base = lds + buf * 32768;
    f16x8 hh0, hh1, ll0, ll1;
    #pragma unroll
    for (int i = 0; i < 16; i++){
      float v = a4[i >> 2][i & 3];
      f16 h = (f16)v;
      f16 l = (f16)(v - (float)h);
      if (i < 8){ hh0[i] = h; ll0[i] = l; } else { hh1[i & 7] = h; ll1[i & 7] = l; }
    }
    int s0 = ((2*halfA)     ^ (rowA & 3)) << 4;
    int s1 = ((2*halfA + 1) ^ (rowA & 3)) << 4;
    *(f16x8*)(base + rowA*64 + s0)        = hh0;
    *(f16x8*)(base + rowA*64 + s1)        = hh1;
    *(f16x8*)(base + 8192 + rowA*64 + s0) = ll0;
    *(f16x8*)(base + 8192 + rowA*64 + s1) = ll1;
  };
  const char* bhig = ws + WS_WIH_HI;
  const char* blog = ws + WS_WIH_LO;
  auto stageB = [&](int buf, int kt){
    long toff = (long)(bn*32 + kt) * 8192;
    #pragma unroll
    for (int i = 0; i < 4; i++){
      int off = (w*4 + i) << 10;
      const char* g = (off < 8192) ? (bhig + toff + off) : (blog + toff + (off - 8192));
      gld16(g + lane*16, lds + buf*32768 + 16384 + off);
    }
  };
  auto compute = [&](int buf){
    const char* base = lds + buf * 32768;
    f16x8 ah[4], al[4], bh[4], bl[4];
    #pragma unroll
    for (int r = 0; r < 4; r++){
      ah[r] = *(const f16x8*)(base + aoff[r]);
      al[r] = *(const f16x8*)(base + 8192 + aoff[r]);
    }
    #pragma unroll
    for (int c = 0; c < 4; c++){
      bh[c] = *(const f16x8*)(base + 16384 + boff[c]);
      bl[c] = *(const f16x8*)(base + 24576 + boff[c]);
    }
    #pragma unroll
    for (int r = 0; r < 4; r++)
      #pragma unroll
      for (int c = 0; c < 4; c++){
        acc[r][c] = __builtin_amdgcn_mfma_f32_16x16x32_f16(ah[r], bh[c], acc[r][c], 0, 0, 0);
        acc[r][c] = __builtin_amdgcn_mfma_f32_16x16x32_f16(ah[r], bl[c], acc[r][c], 0, 0, 0);
        acc[r][c] = __builtin_amdgcn_mfma_f32_16x16x32_f16(al[r], bh[c], acc[r][c], 0, 0, 0);
      }
  };

  loadA(0);
  stageB(0, 0);
  writeA(0);
  __syncthreads();
  #pragma unroll 2
  for (int kt = 0; kt < 32; kt++){
    const int buf = kt & 1;
    if (kt < 31){
      loadA(kt + 1);
      stageB(buf ^ 1, kt + 1);
    }
    compute(buf);
    if (kt < 31) writeA(buf ^ 1);
    __syncthreads();
  }

  const float* bias = (const float*)(ws + WS_BIAS);
  #pragma unroll
  for (int r = 0; r < 4; r++){
    int row0 = qr*64 + r*16 + ((lane >> 4) << 2);
    long gibase = ((long)bm*128 + row0) * 1024;
    #pragma unroll
    for (int c = 0; c < 4; c++){
      int gj = (bn << 7) + qc*64 + c*16 + (lane & 15);
      float bj = bias[gj];
      #pragma unroll
      for (int rr = 0; rr < 4; rr++)
        out[gibase + (long)rr*1024 + gj] = acc[r][c][rr] + bj;
    }
  }
}

// ---- recurrence: 128 WGs x 64 thr (cooperative). WG = (rg: 16 rows) x (cg: 32 cols).
// 4 independent group barriers (32 WGs each, monotonic counters). No L2 flushes.
__global__ __launch_bounds__(64) void k_rnn(char* __restrict__ ws, float* __restrict__ out){
  __shared__ char ldsB[65536];   // Whh-hi [32 cols][1024 k] f16, XOR-swizzled
  const int lane = threadIdx.x;
  const int bid  = blockIdx.x;        // 0..127
  const int rg = bid & 3, cg = bid >> 2;
  const int j0 = cg << 5;             // 32 columns
  const int r0 = rg << 4;             // 16 rows

  { // stage Whh-hi cols j0..j0+31 (64 KB) into LDS once
    const char* gH = ws + WS_WHH_HI + (long)j0 * 2048;
    #pragma unroll 8
    for (int i = 0; i < 64; i++)
      gld16(gH + i*1024 + lane*16, ldsB + i*1024);
  }
  __syncthreads();

  u32* pk0 = (u32*)(ws + WS_HBUF);
  u32* pk1 = (u32*)(ws + WS_HBUF + 262144UL);
  u32* cnt = (u32*)(ws + WS_BAR + (long)rg * 128);

  const int colL = lane & 15;
  const int q    = lane >> 4;
  const int kg   = q << 3;
  const int myrow = r0 + colL;        // A-fragment row (row = lane&15, verified layout)
  const int rowe  = r0 + (q << 2);    // C-fragment row base (row = 4*(lane>>4)+reg)
  const int swz = (colL & 7) << 4;
  const int kg2 = kg * 2;
  const int lb0 = colL * 2048;
  const int lb1 = (16 + colL) * 2048;
  const char* blo0 = ws + WS_WHH_LO + (long)(j0 + colL) * 2048;
  const char* blo1 = ws + WS_WHH_LO + (long)(j0 + 16 + colL) * 2048;
  const int col0 = j0 + colL, col1 = j0 + 16 + colL;

  float p0[4], p1[4];   // pre(t), prefetched
  {
    long ob = (long)rowe * 1024;
    #pragma unroll
    for (int rr = 0; rr < 4; rr++){
      p0[rr] = out[ob + rr*1024 + col0];
      p1[rr] = out[ob + rr*1024 + col1];
    }
  }

  for (int t = 0; t < 512; t++){
    const u32* Ap = (t & 1) ? pk1 : pk0;
    u32*       Np = (t & 1) ? pk0 : pk1;
    const u64* ap = (const u64*)(Ap + (long)myrow * 1024 + kg);

    f32x4 a0a={0.f,0.f,0.f,0.f}, a0b={0.f,0.f,0.f,0.f}, a0c={0.f,0.f,0.f,0.f};
    f32x4 a1a={0.f,0.f,0.f,0.f}, a1b={0.f,0.f,0.f,0.f}, a1c={0.f,0.f,0.f,0.f};

    #pragma unroll 8
    for (int ks = 0; ks < 32; ks++){
      u64 w0 = cload(ap + ks*16 + 0);
      u64 w1 = cload(ap + ks*16 + 1);
      u64 w2 = cload(ap + ks*16 + 2);
      u64 w3 = cload(ap + ks*16 + 3);
      u32 q0=(u32)w0, q1=(u32)(w0>>32), q2=(u32)w1, q3=(u32)(w1>>32);
      u32 q4=(u32)w2, q5=(u32)(w2>>32), q6=(u32)w3, q7=(u32)(w3>>32);
      u32x4 vh = { __builtin_amdgcn_perm(q1,q0,0x05040100u), __builtin_amdgcn_perm(q3,q2,0x05040100u),
                   __builtin_amdgcn_perm(q5,q4,0x05040100u), __builtin_amdgcn_perm(q7,q6,0x05040100u) };
      u32x4 vl = { __builtin_amdgcn_perm(q1,q0,0x07060302u), __builtin_amdgcn_perm(q3,q2,0x07060302u),
                   __builtin_amdgcn_perm(q5,q4,0x07060302u), __builtin_amdgcn_perm(q7,q6,0x07060302u) };
      f16x8 avh = __builtin_bit_cast(f16x8, vh);
      f16x8 avl = __builtin_bit_cast(f16x8, vl);

      const int kb = ks*64 + kg2;
      f16x8 b0h = *(const f16x8*)(ldsB + lb0 + (kb ^ swz));
      f16x8 b0l = *(const f16x8*)(blo0 + kb);
      f16x8 b1h = *(const f16x8*)(ldsB + lb1 + (kb ^ swz));
      f16x8 b1l = *(const f16x8*)(blo1 + kb);

      // 6 independent accumulator chains -> 1 MFMA per chain per ks (no dep stalls)
      a0a = __builtin_amdgcn_mfma_f32_16x16x32_f16(avh, b0h, a0a, 0, 0, 0);
      a0b = __builtin_amdgcn_mfma_f32_16x16x32_f16(avh, b0l, a0b, 0, 0, 0);
      a0c = __builtin_amdgcn_mfma_f32_16x16x32_f16(avl, b0h, a0c, 0, 0, 0);
      a1a = __builtin_amdgcn_mfma_f32_16x16x32_f16(avh, b1h, a1a, 0, 0, 0);
      a1b = __builtin_amdgcn_mfma_f32_16x16x32_f16(avh, b1l, a1b, 0, 0, 0);
      a1c = __builtin_amdgcn_mfma_f32_16x16x32_f16(avl, b1h, a1c, 0, 0, 0);
    }
    f32x4 A0 = a0a + a0b + a0c;
    f32x4 A1 = a1a + a1b + a1c;

    long obase = ((long)t << 16) + (long)rowe * 1024;
    float hv0[4], hv1[4];
    #pragma unroll
    for (int rr = 0; rr < 4; rr++){
      hv0[rr] = fast_tanh(p0[rr] + A0[rr]);
      hv1[rr] = fast_tanh(p1[rr] + A1[rr]);
      int hr = (rowe + rr) << 10;
      cstore(Np + hr + col0, packf16(hv0[rr]));
      cstore(Np + hr + col1, packf16(hv1[rr]));
    }

    if (t < 511){
      // order: h-stores acked at coherence point -> ONE counter inc per WG (lane 0).
      // (Round-2 bug: all 64 lanes incremented -> barrier never blocked.)
      asm volatile("s_waitcnt vmcnt(0)" ::: "memory");
      if (lane == 0)
        __hip_atomic_fetch_add(cnt, 1u, __ATOMIC_RELAXED, __HIP_MEMORY_SCOPE_SYSTEM);

      // off-critical-path work while waiting: out(t) stores + pre(t+1) prefetch
      #pragma unroll
      for (int rr = 0; rr < 4; rr++){
        __builtin_nontemporal_store(hv0[rr], &out[obase + rr*1024 + col0]);
        __builtin_nontemporal_store(hv1[rr], &out[obase + rr*1024 + col1]);
      }
      long nb = obase + 65536;
      #pragma unroll
      for (int rr = 0; rr < 4; rr++){
        p0[rr] = out[nb + rr*1024 + col0];
        p1[rr] = out[nb + rr*1024 + col1];
      }

      const u32 target = (u32)(t + 1) * 32u;
      while (__hip_atomic_load(cnt, __ATOMIC_RELAXED, __HIP_MEMORY_SCOPE_SYSTEM) < target) {}
      __builtin_amdgcn_sched_barrier(0);
    } else {
      #pragma unroll
      for (int rr = 0; rr < 4; rr++){
        __builtin_nontemporal_store(hv0[rr], &out[obase + rr*1024 + col0]);
        __builtin_nontemporal_store(hv1[rr], &out[obase + rr*1024 + col1]);
      }
    }
  }
}

extern "C" void kernel_launch(void* const* d_in, const int* in_sizes, int n_in,
                              void* d_out, int out_size, void* d_ws, size_t ws_size,
                              hipStream_t stream){
  const float* init = (const float*)d_in[0];
  const float* xs   = (const float*)d_in[1];
  const float* Wih  = (const float*)d_in[2];
  const float* bih  = (const float*)d_in[3];
  const float* Whh  = (const float*)d_in[4];
  const float* bhh  = (const float*)d_in[5];
  float* out = (float*)d_out;
  char* ws = (char*)d_ws;
  (void)in_sizes; (void)n_in; (void)out_size; (void)ws_size;   // needs ~8.92 MiB ws

  hipLaunchKernelGGL(k_split_wih, dim3(512),  dim3(256), 0, stream, Wih, ws);
  hipLaunchKernelGGL(k_split_whh, dim3(512),  dim3(256), 0, stream, Whh, ws);
  hipLaunchKernelGGL(k_prep,      dim3(256),  dim3(256), 0, stream, bih, bhh, init, ws);
  hipLaunchKernelGGL(k_gemm,      dim3(2048), dim3(256), 0, stream, xs, (const char*)ws, out);

  void* kargs[] = { (void*)&ws, (void*)&out };
  hipLaunchCooperativeKernel((const void*)k_rnn, dim3(128), dim3(64), kargs, 0, stream);
}